// Round 4
// baseline (559.121 us; speedup 1.0000x reference)
//
#include <hip/hip_runtime.h>
#include <math.h>

constexpr int N_  = 50000;
constexpr int NP_ = 50048;    // rows padded to multiple of 128
constexpr int F_  = 500;
constexpr int FP_ = 512;      // K padded for gemm1
constexpr int E_  = 1600000;
constexpr int PE_ = 400000;
constexpr int H1_ = 128;
constexpr int H2_ = 64;

typedef __attribute__((ext_vector_type(8))) short bf16x8;
typedef __attribute__((ext_vector_type(4))) float f32x4;

__device__ __forceinline__ unsigned short f2bf(float f){
  unsigned u = __builtin_bit_cast(unsigned, f);
  u = (u + 0x7FFFu + ((u >> 16) & 1u)) >> 16;
  return (unsigned short)u;
}
__device__ __forceinline__ float bflo(unsigned v){
  unsigned u = v << 16; return __builtin_bit_cast(float, u);
}
__device__ __forceinline__ float bfhi(unsigned v){
  unsigned u = v & 0xFFFF0000u; return __builtin_bit_cast(float, u);
}
__device__ __forceinline__ float bf1(unsigned short h){
  unsigned u = ((unsigned)h) << 16; return __builtin_bit_cast(float, u);
}
__device__ __forceinline__ unsigned cvtpk(float lo, float hi){
  unsigned r;
  asm("v_cvt_pk_bf16_f32 %0, %1, %2" : "=v"(r) : "v"(lo), "v"(hi));
  return r;
}
__device__ __forceinline__ bf16x8 mkbf(float4 p, float4 q){
  union { unsigned u[4]; bf16x8 v; } U;
  U.u[0] = cvtpk(p.x, p.y); U.u[1] = cvtpk(p.z, p.w);
  U.u[2] = cvtpk(q.x, q.y); U.u[3] = cvtpk(q.z, q.w);
  return U.v;
}

// ---------------- CSR build ----------------

__global__ void k_init(int* __restrict__ cnt, int* __restrict__ cursor){
  int i = blockIdx.x*256 + threadIdx.x;
  if (i < N_){ cnt[i] = 0; cursor[i] = 0; }
}

__global__ void k_count(const int* __restrict__ ei, int* __restrict__ cnt){
  int e = (blockIdx.x*256 + threadIdx.x)*4;
  if (e + 3 < E_){
    int4 d4 = *reinterpret_cast<const int4*>(ei + E_ + e);
    atomicAdd(&cnt[d4.x], 1); atomicAdd(&cnt[d4.y], 1);
    atomicAdd(&cnt[d4.z], 1); atomicAdd(&cnt[d4.w], 1);
  } else {
    for (int i = e; i < E_; ++i) atomicAdd(&cnt[ei[E_ + i]], 1);
  }
}

__global__ void k_scanA(const int* __restrict__ cnt, int* __restrict__ rowptr,
                        float* __restrict__ dinv, int* __restrict__ blocksum){
  __shared__ int sd[256];
  int t = threadIdx.x;
  int base = blockIdx.x*1024 + t*4;
  int4 v = make_int4(0,0,0,0);
  if (base + 3 < N_) v = *reinterpret_cast<const int4*>(cnt + base);
  else {
    if (base     < N_) v.x = cnt[base];
    if (base + 1 < N_) v.y = cnt[base+1];
    if (base + 2 < N_) v.z = cnt[base+2];
    if (base + 3 < N_) v.w = cnt[base+3];
  }
  int s0 = v.x, s1 = s0 + v.y, s2 = s1 + v.z, s3 = s2 + v.w;
  sd[t] = s3;
  __syncthreads();
  for (int off = 1; off < 256; off <<= 1){
    int add = (t >= off) ? sd[t - off] : 0;
    __syncthreads();
    sd[t] += add;
    __syncthreads();
  }
  int excl = sd[t] - s3;
  if (t == 0) blocksum[blockIdx.x] = sd[255];
  if (base     < N_){ rowptr[base]   = excl;      dinv[base]   = rsqrtf((float)(v.x+1)); }
  if (base + 1 < N_){ rowptr[base+1] = excl+s0;   dinv[base+1] = rsqrtf((float)(v.y+1)); }
  if (base + 2 < N_){ rowptr[base+2] = excl+s1;   dinv[base+2] = rsqrtf((float)(v.z+1)); }
  if (base + 3 < N_){ rowptr[base+3] = excl+s2;   dinv[base+3] = rsqrtf((float)(v.w+1)); }
}

__global__ void k_scanB(const int* __restrict__ blocksum, int* __restrict__ blockoff,
                        int* __restrict__ rowptr, int nb){
  if (threadIdx.x == 0 && blockIdx.x == 0){
    int run = 0;
    for (int b = 0; b < nb; ++b){ blockoff[b] = run; run += blocksum[b]; }
    rowptr[N_] = run;
  }
}

__global__ void k_scanC(int* __restrict__ rowptr, const int* __restrict__ blockoff){
  int i = blockIdx.x*256 + threadIdx.x;
  if (i < N_) rowptr[i] += blockoff[i >> 10];
}

__global__ void k_scatter(const int* __restrict__ ei, const int* __restrict__ rowptr,
                          int* __restrict__ cursor, int* __restrict__ csr){
  int e = blockIdx.x*256 + threadIdx.x;
  if (e >= E_) return;
  int s = ei[e], d = ei[E_ + e];
  int p = atomicAdd(&cursor[d], 1);
  csr[rowptr[d] + p] = s;
}

// ---------------- weight conversion ----------------

__global__ void k_cvt_w1(const float* __restrict__ W1, unsigned short* __restrict__ w1t){
  int id = blockIdx.x*256 + threadIdx.x;          // 128*512
  if (id >= H1_*FP_) return;
  int c = id >> 9, k = id & 511;
  w1t[id] = (k < F_) ? f2bf(W1[(size_t)k*H1_ + c]) : (unsigned short)0;
}

__global__ void k_cvt_w2(const float* __restrict__ W2, unsigned short* __restrict__ w2t){
  int id = blockIdx.x*256 + threadIdx.x;          // 64*128
  if (id >= H2_*H1_) return;
  int c = id >> 7, k = id & 127;
  w2t[id] = f2bf(W2[(size_t)k*H2_ + c]);
}

// ---------------- GEMM1: tmp1b = bf16(x) @ W1  (MFMA, 2-deep pipelined) ----------------
// block tile 32 rows x 128 cols; 4 waves, each wave 32x32 (2m x 2n frags); grid 1563

#define LOAD_SLOT(a0,b0,a1,b1,B0,B1,KT) do{ \
  int k0_ = (KT)*32 + lg*8; \
  a0 = b0 = a1 = b1 = make_float4(0.f,0.f,0.f,0.f); \
  if (k0_ + 8 <= F_){ \
    if (r0ok){ a0 = *reinterpret_cast<const float4*>(xp0+k0_); b0 = *reinterpret_cast<const float4*>(xp0+k0_+4); } \
    if (r1ok){ a1 = *reinterpret_cast<const float4*>(xp1+k0_); b1 = *reinterpret_cast<const float4*>(xp1+k0_+4); } \
  } else if (k0_ + 4 <= F_){ \
    if (r0ok) a0 = *reinterpret_cast<const float4*>(xp0+k0_); \
    if (r1ok) a1 = *reinterpret_cast<const float4*>(xp1+k0_); \
  } \
  B0 = *reinterpret_cast<const bf16x8*>(bp0 + k0_); \
  B1 = *reinterpret_cast<const bf16x8*>(bp1 + k0_); \
}while(0)

#define COMPUTE_SLOT(a0,b0,a1,b1,B0,B1) do{ \
  bf16x8 fa0 = mkbf(a0,b0), fa1 = mkbf(a1,b1); \
  acc00 = __builtin_amdgcn_mfma_f32_16x16x32_bf16(fa0, B0, acc00, 0, 0, 0); \
  acc01 = __builtin_amdgcn_mfma_f32_16x16x32_bf16(fa0, B1, acc01, 0, 0, 0); \
  acc10 = __builtin_amdgcn_mfma_f32_16x16x32_bf16(fa1, B0, acc10, 0, 0, 0); \
  acc11 = __builtin_amdgcn_mfma_f32_16x16x32_bf16(fa1, B1, acc11, 0, 0, 0); \
}while(0)

__global__ __launch_bounds__(256) void k_gemm1(const float* __restrict__ x,
    const unsigned short* __restrict__ w1t, unsigned short* __restrict__ tmp1b){
  int tid = threadIdx.x;
  int w = tid >> 6, lane = tid & 63;
  int lr = lane & 15, lg = lane >> 4;
  int row_base = blockIdx.x*32;
  int col_base = w*32;

  int r0 = row_base + lr, r1 = row_base + 16 + lr;
  bool r0ok = r0 < N_, r1ok = r1 < N_;
  const float* xp0 = x + (size_t)r0 * F_;
  const float* xp1 = x + (size_t)r1 * F_;
  const unsigned short* bp0 = w1t + (size_t)(col_base + lr)*FP_;
  const unsigned short* bp1 = w1t + (size_t)(col_base + 16 + lr)*FP_;

  f32x4 acc00 = {0.f,0.f,0.f,0.f}, acc01 = acc00, acc10 = acc00, acc11 = acc00;

  // two named pipeline slots (period-2 rotation, 2-deep lookahead)
  float4 Aa0, Ab0, Aa1, Ab1; bf16x8 AB0, AB1;
  float4 Ba0, Bb0, Ba1, Bb1; bf16x8 BB0, BB1;

  LOAD_SLOT(Aa0,Ab0,Aa1,Ab1,AB0,AB1, 0);
  LOAD_SLOT(Ba0,Bb0,Ba1,Bb1,BB0,BB1, 1);

  #pragma unroll
  for (int kt = 0; kt < 16; kt += 2){
    COMPUTE_SLOT(Aa0,Ab0,Aa1,Ab1,AB0,AB1);
    if (kt + 2 < 16) LOAD_SLOT(Aa0,Ab0,Aa1,Ab1,AB0,AB1, kt+2);
    COMPUTE_SLOT(Ba0,Bb0,Ba1,Bb1,BB0,BB1);
    if (kt + 3 < 16) LOAD_SLOT(Ba0,Bb0,Ba1,Bb1,BB0,BB1, kt+3);
  }

  const f32x4* accs[4] = {&acc00, &acc01, &acc10, &acc11};
  #pragma unroll
  for (int m = 0; m < 2; ++m){
    #pragma unroll
    for (int q = 0; q < 4; ++q){
      int r = row_base + m*16 + lg*4 + q;
      if (r < N_){
        #pragma unroll
        for (int n = 0; n < 2; ++n){
          const f32x4& a = *accs[m*2+n];
          tmp1b[(size_t)r*H1_ + col_base + n*16 + lr] = f2bf(a[q]);
        }
      }
    }
  }
}

// ---------------- Aggregation H=128 (bf16 gather, fp32 acc) + bias + relu -> h1b ----------------

__global__ __launch_bounds__(256) void k_agg128(const unsigned short* __restrict__ tmp1b,
    const int* __restrict__ rowptr, const int* __restrict__ csr,
    const float* __restrict__ dinv, const float* __restrict__ b1,
    unsigned short* __restrict__ h1b){
  int wave = threadIdx.x >> 6, lane = threadIdx.x & 63;
  int n = blockIdx.x*4 + wave;
  if (n >= N_) return;
  float di = dinv[n];
  unsigned self = *reinterpret_cast<const unsigned*>(tmp1b + (size_t)n*H1_ + lane*2);
  float ax = di*di*bflo(self), ay = di*di*bfhi(self);
  int k0 = rowptr[n], k1 = rowptr[n+1];
  int k = k0, kend = k0 + ((k1 - k0) & ~7);
  for (; k < kend; k += 8){
    int s[8]; float wv[8]; unsigned v[8];
    #pragma unroll
    for (int j = 0; j < 8; ++j) s[j] = csr[k+j];
    #pragma unroll
    for (int j = 0; j < 8; ++j){
      wv[j] = dinv[s[j]];
      v[j] = *reinterpret_cast<const unsigned*>(tmp1b + (size_t)s[j]*H1_ + lane*2);
    }
    #pragma unroll
    for (int j = 0; j < 8; ++j){
      float ww = di*wv[j];
      ax += ww*bflo(v[j]); ay += ww*bfhi(v[j]);
    }
  }
  for (; k < k1; ++k){
    int s = csr[k];
    float ww = di*dinv[s];
    unsigned v = *reinterpret_cast<const unsigned*>(tmp1b + (size_t)s*H1_ + lane*2);
    ax += ww*bflo(v); ay += ww*bfhi(v);
  }
  float2 bb = *reinterpret_cast<const float2*>(b1 + lane*2);
  float ox = fmaxf(ax + bb.x, 0.f);
  float oy = fmaxf(ay + bb.y, 0.f);
  unsigned packed = (unsigned)f2bf(ox) | ((unsigned)f2bf(oy) << 16);
  *reinterpret_cast<unsigned*>(h1b + (size_t)n*H1_ + lane*2) = packed;
}

// ---------------- GEMM2: tmp2b = h1b @ W2 (MFMA) ----------------

__global__ __launch_bounds__(256) void k_gemm2(const unsigned short* __restrict__ h1b,
    const unsigned short* __restrict__ w2t, unsigned short* __restrict__ tmp2b){
  int tid = threadIdx.x;
  int w = tid >> 6, lane = tid & 63;
  int lr = lane & 15, lg = lane >> 4;
  int row_base = blockIdx.x*128 + w*32;

  f32x4 acc[2][4];
  #pragma unroll
  for (int m = 0; m < 2; ++m)
    #pragma unroll
    for (int n = 0; n < 4; ++n) acc[m][n] = (f32x4){0.f,0.f,0.f,0.f};

  #pragma unroll
  for (int kt = 0; kt < 4; ++kt){
    int k0 = kt*32 + lg*8;
    bf16x8 a[2];
    #pragma unroll
    for (int m = 0; m < 2; ++m){
      int r = row_base + m*16 + lr;   // r < NP_; pad rows only pollute unstored D rows
      a[m] = *reinterpret_cast<const bf16x8*>(h1b + (size_t)r*H1_ + k0);
    }
    bf16x8 b[4];
    #pragma unroll
    for (int n = 0; n < 4; ++n)
      b[n] = *reinterpret_cast<const bf16x8*>(w2t + (size_t)(n*16 + lr)*H1_ + k0);
    #pragma unroll
    for (int m = 0; m < 2; ++m)
      #pragma unroll
      for (int n = 0; n < 4; ++n)
        acc[m][n] = __builtin_amdgcn_mfma_f32_16x16x32_bf16(a[m], b[n], acc[m][n], 0, 0, 0);
  }

  #pragma unroll
  for (int m = 0; m < 2; ++m){
    #pragma unroll
    for (int q = 0; q < 4; ++q){
      int r = row_base + m*16 + lg*4 + q;
      if (r < N_){
        #pragma unroll
        for (int n = 0; n < 4; ++n)
          tmp2b[(size_t)r*H2_ + n*16 + lr] = f2bf(acc[m][n][q]);
      }
    }
  }
}

// ---------------- Aggregation H=64 + bias -> feat + featb + tmp3 ----------------

__global__ __launch_bounds__(256) void k_agg64(const unsigned short* __restrict__ tmp2b,
    const int* __restrict__ rowptr, const int* __restrict__ csr,
    const float* __restrict__ dinv, const float* __restrict__ b2,
    const float* __restrict__ Wattr, const float* __restrict__ Wattk,
    float* __restrict__ feat, unsigned short* __restrict__ featb,
    float* __restrict__ tmp3){
  int wave = threadIdx.x >> 6, lane = threadIdx.x & 63;
  int n = blockIdx.x*4 + wave;
  if (n >= N_) return;
  float di = dinv[n];
  float acc = di*di*bf1(tmp2b[(size_t)n*H2_ + lane]);
  int k0 = rowptr[n], k1 = rowptr[n+1];
  int k = k0, kend = k0 + ((k1 - k0) & ~7);
  for (; k < kend; k += 8){
    int s[8]; float wv[8]; float v[8];
    #pragma unroll
    for (int j = 0; j < 8; ++j) s[j] = csr[k+j];
    #pragma unroll
    for (int j = 0; j < 8; ++j){
      wv[j] = dinv[s[j]];
      v[j] = bf1(tmp2b[(size_t)s[j]*H2_ + lane]);
    }
    #pragma unroll
    for (int j = 0; j < 8; ++j) acc += di*wv[j]*v[j];
  }
  for (; k < k1; ++k){
    int s = csr[k];
    acc += di*dinv[s]*bf1(tmp2b[(size_t)s*H2_ + lane]);
  }
  float h2v = acc + b2[lane];
  feat[(size_t)n*H2_ + lane] = h2v;
  featb[(size_t)n*H2_ + lane] = f2bf(h2v);

  float p[6];
  p[0] = h2v * Wattr[lane*3+0];
  p[1] = h2v * Wattr[lane*3+1];
  p[2] = h2v * Wattr[lane*3+2];
  p[3] = h2v * Wattk[lane*3+0];
  p[4] = h2v * Wattk[lane*3+1];
  p[5] = h2v * Wattk[lane*3+2];
  #pragma unroll
  for (int c = 0; c < 6; ++c){
    float v = p[c];
    #pragma unroll
    for (int off = 1; off < 64; off <<= 1) v += __shfl_xor(v, off, 64);
    p[c] = v;
  }
  if (lane == 0){
    float* tp = tmp3 + (size_t)n*6;
    tp[0]=p[0]; tp[1]=p[1]; tp[2]=p[2]; tp[3]=p[3]; tp[4]=p[4]; tp[5]=p[5];
  }
}

// ---------------- Aggregation over 6 cols (4 lanes/node) + log_softmax ----------------

__global__ void k_agg6(const float* __restrict__ tmp3,
    const int* __restrict__ rowptr, const int* __restrict__ csr,
    const float* __restrict__ dinv, const float* __restrict__ battr,
    const float* __restrict__ battk, float* __restrict__ out_ls,
    float* __restrict__ out_att){
  int tid = blockIdx.x*256 + threadIdx.x;
  int n = tid >> 2, q = tid & 3;
  if (n >= N_) return;
  float di = dinv[n];
  float a[6] = {0.f,0.f,0.f,0.f,0.f,0.f};
  if (q == 0){
    const float* tp = tmp3 + (size_t)n*6;
    #pragma unroll
    for (int c = 0; c < 6; ++c) a[c] = di*di*tp[c];
  }
  int k0 = rowptr[n], k1 = rowptr[n+1];
  for (int k = k0 + q; k < k1; k += 4){
    int s = csr[k];
    float w = di*dinv[s];
    const float* sp = tmp3 + (size_t)s*6;
    #pragma unroll
    for (int c = 0; c < 6; ++c) a[c] += w*sp[c];
  }
  #pragma unroll
  for (int c = 0; c < 6; ++c){
    a[c] += __shfl_xor(a[c], 1, 64);
    a[c] += __shfl_xor(a[c], 2, 64);
  }
  if (q == 0){
    float t0 = a[0]+battr[0], t1 = a[1]+battr[1], t2 = a[2]+battr[2];
    float m = fmaxf(t0, fmaxf(t1, t2));
    float l = logf(expf(t0-m)+expf(t1-m)+expf(t2-m));
    out_ls[(size_t)n*3+0] = t0-m-l;
    out_ls[(size_t)n*3+1] = t1-m-l;
    out_ls[(size_t)n*3+2] = t2-m-l;
    out_att[(size_t)n*3+0] = a[3]+battk[0];
    out_att[(size_t)n*3+1] = a[4]+battk[1];
    out_att[(size_t)n*3+2] = a[5]+battk[2];
  }
}

// ---------------- Edge dot products (bf16 feat, 8 lanes/edge, 2 edges/group) ----------------

__global__ __launch_bounds__(256) void k_res(const unsigned short* __restrict__ featb,
    const int* __restrict__ pe, const int* __restrict__ ne,
    float* __restrict__ res){
  int gid = blockIdx.x*256 + threadIdx.x;
  int grp = gid >> 3, l = gid & 7;
  int e0 = grp*2;
  if (e0 >= 2*PE_) return;
  const int* src; int base;
  if (e0 < PE_){ src = pe; base = e0; }
  else         { src = ne; base = e0 - PE_; }
  int u0 = src[base],   w0 = src[PE_ + base];
  int u1 = src[base+1], w1 = src[PE_ + base + 1];
  uint4 A0 = *reinterpret_cast<const uint4*>(featb + (size_t)u0*H2_ + l*8);
  uint4 B0 = *reinterpret_cast<const uint4*>(featb + (size_t)w0*H2_ + l*8);
  uint4 A1 = *reinterpret_cast<const uint4*>(featb + (size_t)u1*H2_ + l*8);
  uint4 B1 = *reinterpret_cast<const uint4*>(featb + (size_t)w1*H2_ + l*8);
  float s0 = bflo(A0.x)*bflo(B0.x) + bfhi(A0.x)*bfhi(B0.x)
           + bflo(A0.y)*bflo(B0.y) + bfhi(A0.y)*bfhi(B0.y)
           + bflo(A0.z)*bflo(B0.z) + bfhi(A0.z)*bfhi(B0.z)
           + bflo(A0.w)*bflo(B0.w) + bfhi(A0.w)*bfhi(B0.w);
  float s1 = bflo(A1.x)*bflo(B1.x) + bfhi(A1.x)*bfhi(B1.x)
           + bflo(A1.y)*bflo(B1.y) + bfhi(A1.y)*bfhi(B1.y)
           + bflo(A1.z)*bflo(B1.z) + bfhi(A1.z)*bfhi(B1.z)
           + bflo(A1.w)*bflo(B1.w) + bfhi(A1.w)*bfhi(B1.w);
  #pragma unroll
  for (int off = 1; off < 8; off <<= 1){
    s0 += __shfl_xor(s0, off, 64);
    s1 += __shfl_xor(s1, off, 64);
  }
  if (l == 0) *reinterpret_cast<float2*>(res + e0) = make_float2(s0, s1);
}

// ---------------- launch ----------------

extern "C" void kernel_launch(void* const* d_in, const int* in_sizes, int n_in,
                              void* d_out, int out_size, void* d_ws, size_t ws_size,
                              hipStream_t stream) {
  const float* x     = (const float*)d_in[0];
  // d_in[1] = glove (identity) — algebraically skipped
  const float* W1    = (const float*)d_in[2];
  const float* b1    = (const float*)d_in[3];
  const float* W2    = (const float*)d_in[4];
  const float* b2    = (const float*)d_in[5];
  const float* Wattr = (const float*)d_in[6];
  const float* battr = (const float*)d_in[7];
  const float* Wattk = (const float*)d_in[8];
  const float* battk = (const float*)d_in[9];
  const int*   ei    = (const int*)d_in[10];
  const int*   pe    = (const int*)d_in[11];
  const int*   ne    = (const int*)d_in[12];

  char* ws = (char*)d_ws;
  size_t off = 0;
  auto alloc = [&](size_t bytes)->char*{
    char* p = ws + off;
    off = (off + bytes + 255) & ~(size_t)255;
    return p;
  };
  int*   cnt      = (int*)  alloc((size_t)N_*4);
  int*   cursor   = (int*)  alloc((size_t)N_*4);
  int*   rowptr   = (int*)  alloc((size_t)(N_+1)*4);
  int*   blocksum = (int*)  alloc(64*4);
  int*   blockoff = (int*)  alloc(64*4);
  float* dinv     = (float*)alloc((size_t)N_*4);
  int*   csr      = (int*)  alloc((size_t)E_*4);
  unsigned short* w1t   = (unsigned short*)alloc((size_t)H1_*FP_*2);
  unsigned short* w2t   = (unsigned short*)alloc((size_t)H2_*H1_*2);
  unsigned short* tmp1b = (unsigned short*)alloc((size_t)NP_*H1_*2);
  unsigned short* h1b   = (unsigned short*)alloc((size_t)NP_*H1_*2);
  unsigned short* tmp2b = (unsigned short*)alloc((size_t)NP_*H2_*2);
  // tmp1b dead after k_agg128 -> reuse for featb (6.4MB) + tmp3 (1.2MB)
  unsigned short* featb = tmp1b;
  float* tmp3 = (float*)((char*)tmp1b + (size_t)N_*H2_*2 + 128);

  float* out   = (float*)d_out;
  float* res   = out;                       // 800000
  float* o_ls  = out + 800000;              // 150000
  float* o_att = out + 950000;              // 150000
  float* feat  = out + 1100000;             // 3200000

  const int NB = (N_ + 1023) / 1024;        // 49

  k_init   <<<(N_+255)/256, 256, 0, stream>>>(cnt, cursor);
  k_count  <<<(E_/4+255)/256, 256, 0, stream>>>(ei, cnt);
  k_scanA  <<<NB, 256, 0, stream>>>(cnt, rowptr, dinv, blocksum);
  k_scanB  <<<1, 64, 0, stream>>>(blocksum, blockoff, rowptr, NB);
  k_scanC  <<<(N_+255)/256, 256, 0, stream>>>(rowptr, blockoff);
  k_scatter<<<(E_+255)/256, 256, 0, stream>>>(ei, rowptr, cursor, csr);

  k_cvt_w1 <<<(H1_*FP_+255)/256, 256, 0, stream>>>(W1, w1t);
  k_cvt_w2 <<<(H2_*H1_+255)/256, 256, 0, stream>>>(W2, w2t);

  k_gemm1  <<<(N_+31)/32, 256, 0, stream>>>(x, w1t, tmp1b);
  k_agg128 <<<(N_+3)/4, 256, 0, stream>>>(tmp1b, rowptr, csr, dinv, b1, h1b);
  k_gemm2  <<<NP_/128, 256, 0, stream>>>(h1b, w2t, tmp2b);
  k_agg64  <<<(N_+3)/4, 256, 0, stream>>>(tmp2b, rowptr, csr, dinv, b2,
                                          Wattr, Wattk, feat, featb, tmp3);
  k_agg6   <<<(N_*4+255)/256, 256, 0, stream>>>(tmp3, rowptr, csr, dinv,
                                                battr, battk, o_ls, o_att);
  k_res    <<<(PE_*8+255)/256, 256, 0, stream>>>(featb, pe, ne, res);
}